// Round 3
// baseline (633.722 us; speedup 1.0000x reference)
//
#include <hip/hip_runtime.h>

// GCN 3-layer: h = relu(Ahat @ (h W) + b) x2, then Ahat @ (h W2) + b2.
// Ahat = D^-1/2 (A + I) D^-1/2.
// Trick: GEMM epilogue pre-scales rows by dinv[row] (t' = dinv*(A W)), so
// aggregation is a pure gather-sum: h_i = relu(dinv_i * (sum t'[nbr] + t'[i]) + b).

static inline size_t alignup(size_t x, size_t a) { return (x + a - 1) & ~(a - 1); }

__global__ __launch_bounds__(256) void k_fill_i32(int* __restrict__ p, int v, int n) {
    int i = blockIdx.x * 256 + threadIdx.x;
    if (i < n) p[i] = v;
}

__global__ __launch_bounds__(256) void k_count_deg(const int* __restrict__ dst, int* __restrict__ deg, int E) {
    int e = blockIdx.x * 256 + threadIdx.x;
    if (e < E) atomicAdd(&deg[dst[e]], 1);
}

__global__ __launch_bounds__(256) void k_dinv(const int* __restrict__ deg, float* __restrict__ dinv, int n) {
    int i = blockIdx.x * 256 + threadIdx.x;
    if (i < n) dinv[i] = rsqrtf((float)deg[i] + 1.0f);  // +1 self-loop; always > 0
}

// ---- exclusive scan of deg -> row_start ----
__global__ __launch_bounds__(256) void k_scan1(const int* __restrict__ deg, int* __restrict__ rs,
                                               int* __restrict__ bsum, int n) {
    __shared__ int sd[256];
    int b = blockIdx.x, tid = threadIdx.x;
    int base = b * 1024 + tid * 4;
    int v[4];
#pragma unroll
    for (int j = 0; j < 4; ++j) v[j] = (base + j < n) ? deg[base + j] : 0;
    int tot = v[0] + v[1] + v[2] + v[3];
    sd[tid] = tot;
    for (int off = 1; off < 256; off <<= 1) {
        __syncthreads();
        int t = (tid >= off) ? sd[tid - off] : 0;
        __syncthreads();
        sd[tid] += t;
    }
    __syncthreads();
    int run = tid ? sd[tid - 1] : 0;
#pragma unroll
    for (int j = 0; j < 4; ++j) {
        if (base + j < n) rs[base + j] = run;
        run += v[j];
    }
    if (tid == 255) bsum[b] = sd[255];
}

__global__ __launch_bounds__(256) void k_scan2(int* __restrict__ bsum, int nb) {
    __shared__ int sd[256];
    int tid = threadIdx.x;
    sd[tid] = (tid < nb) ? bsum[tid] : 0;
    for (int off = 1; off < 256; off <<= 1) {
        __syncthreads();
        int t = (tid >= off) ? sd[tid - off] : 0;
        __syncthreads();
        sd[tid] += t;
    }
    __syncthreads();
    if (tid < nb) bsum[tid] = tid ? sd[tid - 1] : 0;
}

__global__ __launch_bounds__(256) void k_scan3(int* __restrict__ rs, int* __restrict__ cursor,
                                               const int* __restrict__ bsum, int n, int E) {
    int b = blockIdx.x, tid = threadIdx.x;
    int off = bsum[b];
    int base = b * 1024 + tid * 4;
#pragma unroll
    for (int j = 0; j < 4; ++j) {
        int idx = base + j;
        if (idx < n) {
            int v = rs[idx] + off;
            rs[idx] = v;
            cursor[idx] = v;
        }
    }
    if (b == 0 && tid == 0) rs[n] = E;
}

__global__ __launch_bounds__(256) void k_fill_csr(const int* __restrict__ src, const int* __restrict__ dst,
                                                  int* __restrict__ cursor, int* __restrict__ col, int E) {
    int e = blockIdx.x * 256 + threadIdx.x;
    if (e < E) {
        int d = dst[e];
        int pos = atomicAdd(&cursor[d], 1);
        col[pos] = src[e];
    }
}

// ---- f32 GEMM + dinv row-prescale: C[r][c] = dinv[r] * sum_k A[r][k] B[k][c] ----
// 128x64 tile, BK=16, 256 threads, 8x4 microtile.
#define BM 128
#define BN 64
#define BK 16

__global__ __launch_bounds__(256) void k_gemm(const float* __restrict__ A, const float* __restrict__ B,
                                              float* __restrict__ C, const float* __restrict__ dinv,
                                              int N) {
    __shared__ float As[BK][BM + 4];
    __shared__ float Bs[BK][BN];
    int tid = threadIdx.x;
    int bx = blockIdx.x, by = blockIdx.y;
    int tx = tid & 15, ty = tid >> 4;  // tx: col group (4 cols), ty: row group (8 rows)
    int row0 = by * BM;
    float acc[8][4] = {};
    int ar = tid >> 2, ac = (tid & 3) << 2;   // A tile: 128 rows x 16 cols, 2 float4/thread
    int br = tid >> 4, bc = (tid & 15) << 2;  // B tile: 16 rows x 64 cols, 1 float4/thread

    for (int k0 = 0; k0 < 256; k0 += BK) {
#pragma unroll
        for (int half = 0; half < 2; ++half) {
            int r = ar + half * 64;
            int grow = row0 + r;
            float4 av = make_float4(0.f, 0.f, 0.f, 0.f);
            if (grow < N) av = *(const float4*)(A + (size_t)grow * 256 + k0 + ac);
            As[ac + 0][r] = av.x;
            As[ac + 1][r] = av.y;
            As[ac + 2][r] = av.z;
            As[ac + 3][r] = av.w;
        }
        float4 bv = *(const float4*)(B + (size_t)(k0 + br) * 256 + bx * BN + bc);
        *(float4*)&Bs[br][bc] = bv;
        __syncthreads();
#pragma unroll
        for (int k = 0; k < BK; ++k) {
            float4 a0 = *(const float4*)&As[k][ty << 3];
            float4 a1 = *(const float4*)&As[k][(ty << 3) + 4];
            float4 b4 = *(const float4*)&Bs[k][tx << 2];
            float a[8] = {a0.x, a0.y, a0.z, a0.w, a1.x, a1.y, a1.z, a1.w};
            float b[4] = {b4.x, b4.y, b4.z, b4.w};
#pragma unroll
            for (int i = 0; i < 8; ++i)
#pragma unroll
                for (int j = 0; j < 4; ++j) acc[i][j] = fmaf(a[i], b[j], acc[i][j]);
        }
        __syncthreads();
    }
#pragma unroll
    for (int i = 0; i < 8; ++i) {
        int grow = row0 + (ty << 3) + i;
        if (grow < N) {
            float d = dinv[grow];
            *(float4*)(C + (size_t)grow * 256 + bx * BN + (tx << 2)) =
                make_float4(d * acc[i][0], d * acc[i][1], d * acc[i][2], d * acc[i][3]);
        }
    }
}

// ---- aggregation over prescaled t': one wave per (node, 64-feature quarter) ----
// h[i,f] = relu?(dinv_i * (sum_{s in N(i)} t'[s,f] + t'[i,f]) + b[f])
__global__ __launch_bounds__(256) void k_agg(const float* __restrict__ t, float* __restrict__ h,
                                             const int* __restrict__ rs, const int* __restrict__ col,
                                             const float* __restrict__ dinv, const float* __restrict__ bias,
                                             int N, int do_relu) {
    int node = blockIdx.x;
    int q = threadIdx.x >> 6;    // feature quarter 0..3
    int lane = threadIdx.x & 63;
    int f = (q << 6) + lane;
    if (node >= N) return;

    float acc = t[(size_t)node * 256 + f];  // self term (already dinv-scaled)
    int e0 = rs[node], e1 = rs[node + 1];
    for (int base = e0; base < e1; base += 64) {
        int m = e1 - base; if (m > 64) m = 64;
        int c = (base + lane < e1) ? col[base + lane] : 0;
        int j = 0;
        for (; j + 4 <= m; j += 4) {
            int s0 = __shfl(c, j);
            int s1 = __shfl(c, j + 1);
            int s2 = __shfl(c, j + 2);
            int s3 = __shfl(c, j + 3);
            float v0 = t[(size_t)s0 * 256 + f];
            float v1 = t[(size_t)s1 * 256 + f];
            float v2 = t[(size_t)s2 * 256 + f];
            float v3 = t[(size_t)s3 * 256 + f];
            acc += (v0 + v1) + (v2 + v3);
        }
        for (; j < m; ++j) {
            int s = __shfl(c, j);
            acc += t[(size_t)s * 256 + f];
        }
    }
    float o = fmaf(dinv[node], acc, bias[f]);
    if (do_relu) o = fmaxf(o, 0.f);
    h[(size_t)node * 256 + f] = o;
}

// ---- z'[i] = dinv_i * dot(h[i,:], W2[:,0]) — one wave per node ----
__global__ __launch_bounds__(256) void k_gemv(const float* __restrict__ h, const float* __restrict__ w,
                                              const float* __restrict__ dinv, float* __restrict__ z, int N) {
    int wid = (blockIdx.x * 256 + threadIdx.x) >> 6;
    int lane = threadIdx.x & 63;
    if (wid >= N) return;
    float4 hv = ((const float4*)(h + (size_t)wid * 256))[lane];
    float4 wv = ((const float4*)w)[lane];
    float s = hv.x * wv.x + hv.y * wv.y + hv.z * wv.z + hv.w * wv.w;
#pragma unroll
    for (int off = 32; off > 0; off >>= 1) s += __shfl_down(s, off, 64);
    if (lane == 0) z[wid] = dinv[wid] * s;
}

// ---- out_i = dinv_i * (sum z'[nbr] + z'[i]) + b2 — one wave per node, lane-parallel edges ----
__global__ __launch_bounds__(256) void k_agg_out(const float* __restrict__ z, float* __restrict__ out,
                                                 const int* __restrict__ rs, const int* __restrict__ col,
                                                 const float* __restrict__ dinv, const float* __restrict__ b2,
                                                 int N) {
    int wid = (blockIdx.x * 256 + threadIdx.x) >> 6;
    int lane = threadIdx.x & 63;
    if (wid >= N) return;
    int e0 = rs[wid], e1 = rs[wid + 1];
    float v = 0.f;
    for (int base = e0; base < e1; base += 64) {
        int e = base + lane;
        if (e < e1) v += z[col[e]];
    }
#pragma unroll
    for (int off = 32; off > 0; off >>= 1) v += __shfl_down(v, off, 64);
    if (lane == 0) out[wid] = fmaf(dinv[wid], v + z[wid], b2[0]);
}

extern "C" void kernel_launch(void* const* d_in, const int* in_sizes, int n_in,
                              void* d_out, int out_size, void* d_ws, size_t ws_size,
                              hipStream_t stream) {
    const float* x  = (const float*)d_in[0];
    const int*   ei = (const int*)d_in[1];
    const float* W0 = (const float*)d_in[2];
    const float* b0 = (const float*)d_in[3];
    const float* W1 = (const float*)d_in[4];
    const float* b1 = (const float*)d_in[5];
    const float* W2 = (const float*)d_in[6];
    const float* b2 = (const float*)d_in[7];
    float* out = (float*)d_out;

    int N = in_sizes[0] / 256;
    int E = in_sizes[1] / 2;
    const int* esrc = ei;
    const int* edst = ei + E;

    char* p = (char*)d_ws;
    float* t = (float*)p;      p += (size_t)N * 256 * 4;
    float* h = (float*)p;      p += (size_t)N * 256 * 4;
    float* z = (float*)p;      p += alignup((size_t)N * 4, 16);
    float* dinv = (float*)p;   p += alignup((size_t)N * 4, 16);
    int* deg = (int*)p;        p += alignup((size_t)N * 4, 16);
    int* cursor = (int*)p;     p += alignup((size_t)N * 4, 16);
    int* rs = (int*)p;         p += alignup((size_t)(N + 1) * 4, 16);
    int* col = (int*)p;        p += alignup((size_t)E * 4, 16);
    int* bsum = (int*)p;       p += 256 * 4;

    int nb = (N + 1023) / 1024;
    dim3 blk(256);

    k_fill_i32<<<(N + 255) / 256, blk, 0, stream>>>(deg, 0, N);
    k_count_deg<<<(E + 255) / 256, blk, 0, stream>>>(edst, deg, E);
    k_dinv<<<(N + 255) / 256, blk, 0, stream>>>(deg, dinv, N);
    k_scan1<<<nb, blk, 0, stream>>>(deg, rs, bsum, N);
    k_scan2<<<1, blk, 0, stream>>>(bsum, nb);
    k_scan3<<<nb, blk, 0, stream>>>(rs, cursor, bsum, N, E);
    k_fill_csr<<<(E + 255) / 256, blk, 0, stream>>>(esrc, edst, cursor, col, E);

    dim3 g0(256 / BN, (N + BM - 1) / BM);
    k_gemm<<<g0, blk, 0, stream>>>(x, W0, t, dinv, N);
    k_agg<<<N, blk, 0, stream>>>(t, h, rs, col, dinv, b0, N, 1);
    k_gemm<<<g0, blk, 0, stream>>>(h, W1, t, dinv, N);
    k_agg<<<N, blk, 0, stream>>>(t, h, rs, col, dinv, b1, N, 1);
    k_gemv<<<(N + 3) / 4, blk, 0, stream>>>(h, W2, dinv, z, N);
    k_agg_out<<<(N + 3) / 4, blk, 0, stream>>>(z, out, rs, col, dinv, b2, N);
}

// Round 5
// 394.679 us; speedup vs baseline: 1.6057x; 1.6057x over previous
//
#include <hip/hip_runtime.h>

// GCN 3-layer, bf16 datapath:
//   t' = bf16( dinv[row] * (A @ W) )   via MFMA GEMM (f32 accum)
//   h  = relu( dinv_i * (sum_{nbr} t'[s] + t'[i]) + b )   (bf16 gather, f32 accum)
// Layer 2 is a gemv + scalar aggregation in f32.

static inline size_t alignup(size_t x, size_t a) { return (x + a - 1) & ~(a - 1); }

typedef __attribute__((ext_vector_type(8))) short short8;
typedef __attribute__((ext_vector_type(4))) float f32x4;

__device__ inline unsigned short f2bf(float f) {
    union { float f; unsigned int u; } v; v.f = f;
    unsigned int r = v.u + 0x7FFFu + ((v.u >> 16) & 1u);  // RTNE
    return (unsigned short)(r >> 16);
}
__device__ inline float bf2f(unsigned short u) {
    union { unsigned int u; float f; } v; v.u = ((unsigned int)u) << 16;
    return v.f;
}

// ---------------- preprocessing ----------------
__global__ __launch_bounds__(256) void k_fill_i32(int* __restrict__ p, int v, int n) {
    int i = blockIdx.x * 256 + threadIdx.x;
    if (i < n) p[i] = v;
}

__global__ __launch_bounds__(256) void k_count_deg(const int* __restrict__ dst, int* __restrict__ deg, int E) {
    int e = blockIdx.x * 256 + threadIdx.x;
    if (e < E) atomicAdd(&deg[dst[e]], 1);
}

__global__ __launch_bounds__(256) void k_dinv(const int* __restrict__ deg, float* __restrict__ dinv, int n) {
    int i = blockIdx.x * 256 + threadIdx.x;
    if (i < n) dinv[i] = rsqrtf((float)deg[i] + 1.0f);  // +1 self-loop
}

__global__ __launch_bounds__(256) void k_scan1(const int* __restrict__ deg, int* __restrict__ rs,
                                               int* __restrict__ bsum, int n) {
    __shared__ int sd[256];
    int b = blockIdx.x, tid = threadIdx.x;
    int base = b * 1024 + tid * 4;
    int v[4];
#pragma unroll
    for (int j = 0; j < 4; ++j) v[j] = (base + j < n) ? deg[base + j] : 0;
    int tot = v[0] + v[1] + v[2] + v[3];
    sd[tid] = tot;
    for (int off = 1; off < 256; off <<= 1) {
        __syncthreads();
        int t = (tid >= off) ? sd[tid - off] : 0;
        __syncthreads();
        sd[tid] += t;
    }
    __syncthreads();
    int run = tid ? sd[tid - 1] : 0;
#pragma unroll
    for (int j = 0; j < 4; ++j) {
        if (base + j < n) rs[base + j] = run;
        run += v[j];
    }
    if (tid == 255) bsum[b] = sd[255];
}

__global__ __launch_bounds__(256) void k_scan2(int* __restrict__ bsum, int nb) {
    __shared__ int sd[256];
    int tid = threadIdx.x;
    sd[tid] = (tid < nb) ? bsum[tid] : 0;
    for (int off = 1; off < 256; off <<= 1) {
        __syncthreads();
        int t = (tid >= off) ? sd[tid - off] : 0;
        __syncthreads();
        sd[tid] += t;
    }
    __syncthreads();
    if (tid < nb) bsum[tid] = tid ? sd[tid - 1] : 0;
}

__global__ __launch_bounds__(256) void k_scan3(int* __restrict__ rs, int* __restrict__ cursor,
                                               const int* __restrict__ bsum, int n, int E) {
    int b = blockIdx.x, tid = threadIdx.x;
    int off = bsum[b];
    int base = b * 1024 + tid * 4;
#pragma unroll
    for (int j = 0; j < 4; ++j) {
        int idx = base + j;
        if (idx < n) {
            int v = rs[idx] + off;
            rs[idx] = v;
            cursor[idx] = v;
        }
    }
    if (b == 0 && tid == 0) rs[n] = E;
}

__global__ __launch_bounds__(256) void k_fill_csr(const int* __restrict__ src, const int* __restrict__ dst,
                                                  int* __restrict__ cursor, int* __restrict__ col, int E) {
    int e = blockIdx.x * 256 + threadIdx.x;
    if (e < E) {
        int d = dst[e];
        int pos = atomicAdd(&cursor[d], 1);
        col[pos] = src[e];
    }
}

// ---- W (f32 [k][n]) -> Wt (bf16 [n][k]) ----
__global__ __launch_bounds__(256) void k_wt(const float* __restrict__ W, unsigned short* __restrict__ Wt) {
    int idx = blockIdx.x * 256 + threadIdx.x;  // 65536
    int k = idx >> 8, n = idx & 255;
    Wt[(size_t)n * 256 + k] = f2bf(W[(size_t)k * 256 + n]);  // coalesced read
}

// ---------------- MFMA GEMM ----------------
// C[r][c] = bf16( dinv[r] * sum_k A[r][k]*W[k][c] ),  A f32 [N][256], Wt bf16 [c][k].
// 128x128 tile, BK=32, 4 waves (2x2), 16 MFMA(16x16x32)/wave/K-step.
// LDS fragment-major layout: elem(r,k) at ushort idx (r>>4)*512 + (k>>3)*128 + (r&15)*8 + (k&7)
// -> all ds_read_b128 / ds_write_b128 conflict-free.
__global__ __launch_bounds__(256) void k_gemm_mfma(const float* __restrict__ A,
                                                   const unsigned short* __restrict__ Wt,
                                                   unsigned short* __restrict__ C,
                                                   const float* __restrict__ dinv, int N) {
    __shared__ __align__(16) unsigned short As2[128 * 32];
    __shared__ __align__(16) unsigned short Bs2[128 * 32];
    __shared__ __align__(16) unsigned short Cs[4 * 64 * 64];

    int tid = threadIdx.x;
    int lane = tid & 63, w = tid >> 6;
    int wr = w >> 1, wc = w & 1;
    int row0 = blockIdx.y * 128, col0 = blockIdx.x * 128;

    f32x4 acc[4][4];
#pragma unroll
    for (int m = 0; m < 4; ++m)
#pragma unroll
        for (int n = 0; n < 4; ++n) acc[m][n] = (f32x4)0.f;

    for (int k0 = 0; k0 < 256; k0 += 32) {
        // stage A (f32 -> bf16): 512 chunks of 8 k-elems
#pragma unroll
        for (int it = 0; it < 2; ++it) {
            int c = tid + it * 256;
            int r = c >> 2, kg = c & 3;
            int grow = row0 + r;
            float4 f0 = make_float4(0.f, 0.f, 0.f, 0.f), f1 = f0;
            if (grow < N) {
                const float* g = A + (size_t)grow * 256 + k0 + kg * 8;
                f0 = *(const float4*)g;
                f1 = *(const float4*)(g + 4);
            }
            short8 u;
            u[0] = (short)f2bf(f0.x); u[1] = (short)f2bf(f0.y);
            u[2] = (short)f2bf(f0.z); u[3] = (short)f2bf(f0.w);
            u[4] = (short)f2bf(f1.x); u[5] = (short)f2bf(f1.y);
            u[6] = (short)f2bf(f1.z); u[7] = (short)f2bf(f1.w);
            *(short8*)&As2[(r >> 4) * 512 + kg * 128 + (r & 15) * 8] = u;
        }
        // stage B (bf16 direct 16B loads)
#pragma unroll
        for (int it = 0; it < 2; ++it) {
            int c = tid + it * 256;
            int n = c >> 2, kg = c & 3;
            short8 u = *(const short8*)(Wt + (size_t)(col0 + n) * 256 + k0 + kg * 8);
            *(short8*)&Bs2[(n >> 4) * 512 + kg * 128 + (n & 15) * 8] = u;
        }
        __syncthreads();
        short8 af[4], bfr[4];
#pragma unroll
        for (int m = 0; m < 4; ++m)
            af[m] = *(const short8*)&As2[(wr * 4 + m) * 512 + (lane >> 4) * 128 + (lane & 15) * 8];
#pragma unroll
        for (int n = 0; n < 4; ++n)
            bfr[n] = *(const short8*)&Bs2[(wc * 4 + n) * 512 + (lane >> 4) * 128 + (lane & 15) * 8];
#pragma unroll
        for (int m = 0; m < 4; ++m)
#pragma unroll
            for (int n = 0; n < 4; ++n)
                acc[m][n] = __builtin_amdgcn_mfma_f32_16x16x32_bf16(af[m], bfr[n], acc[m][n], 0, 0, 0);
        __syncthreads();
    }

    // epilogue: scale by dinv, bf16, stage in LDS, coalesced 16B stores
    unsigned short* myCs = &Cs[w * 4096];
#pragma unroll
    for (int m = 0; m < 4; ++m) {
#pragma unroll
        for (int j = 0; j < 4; ++j) {
            int r = m * 16 + (lane >> 4) * 4 + j;  // row within wave tile (D: row=(l>>4)*4+reg)
            int grow = row0 + wr * 64 + r;
            float d = (grow < N) ? dinv[grow] : 0.f;
#pragma unroll
            for (int n = 0; n < 4; ++n)
                myCs[r * 64 + n * 16 + (lane & 15)] = f2bf(acc[m][n][j] * d);  // D: col=l&15
        }
    }
    __syncthreads();
#pragma unroll
    for (int i = 0; i < 8; ++i) {
        int r = i * 8 + (lane >> 3);
        int grow = row0 + wr * 64 + r;
        if (grow < N) {
            short8 v = *(const short8*)&myCs[r * 64 + (lane & 7) * 8];
            *(short8*)(C + (size_t)grow * 256 + col0 + wc * 64 + (lane & 7) * 8) = v;
        }
    }
}

// ---------------- aggregation over bf16 t' ----------------
// one wave per node; lane holds features 4l..4l+3 (8B bf16 load per gathered row)
__global__ __launch_bounds__(256) void k_agg(const unsigned short* __restrict__ t, float* __restrict__ h,
                                             const int* __restrict__ rs, const int* __restrict__ col,
                                             const float* __restrict__ dinv, const float* __restrict__ bias,
                                             int N, int do_relu) {
    int wid = (blockIdx.x * 256 + threadIdx.x) >> 6;
    int lane = threadIdx.x & 63;
    if (wid >= N) return;
    const ushort4* tp = (const ushort4*)t;

    ushort4 sv = tp[(size_t)wid * 64 + lane];  // self term
    float a0 = bf2f(sv.x), a1 = bf2f(sv.y), a2 = bf2f(sv.z), a3 = bf2f(sv.w);

    int e0 = rs[wid], e1 = rs[wid + 1];
    for (int base = e0; base < e1; base += 64) {
        int m = e1 - base; if (m > 64) m = 64;
        int c = (base + lane < e1) ? col[base + lane] : 0;
        int j = 0;
        for (; j + 4 <= m; j += 4) {
            int s0 = __shfl(c, j), s1 = __shfl(c, j + 1), s2 = __shfl(c, j + 2), s3 = __shfl(c, j + 3);
            ushort4 v0 = tp[(size_t)s0 * 64 + lane];
            ushort4 v1 = tp[(size_t)s1 * 64 + lane];
            ushort4 v2 = tp[(size_t)s2 * 64 + lane];
            ushort4 v3 = tp[(size_t)s3 * 64 + lane];
            a0 += (bf2f(v0.x) + bf2f(v1.x)) + (bf2f(v2.x) + bf2f(v3.x));
            a1 += (bf2f(v0.y) + bf2f(v1.y)) + (bf2f(v2.y) + bf2f(v3.y));
            a2 += (bf2f(v0.z) + bf2f(v1.z)) + (bf2f(v2.z) + bf2f(v3.z));
            a3 += (bf2f(v0.w) + bf2f(v1.w)) + (bf2f(v2.w) + bf2f(v3.w));
        }
        for (; j < m; ++j) {
            int s = __shfl(c, j);
            ushort4 v = tp[(size_t)s * 64 + lane];
            a0 += bf2f(v.x); a1 += bf2f(v.y); a2 += bf2f(v.z); a3 += bf2f(v.w);
        }
    }
    float d = dinv[wid];
    float4 bv = ((const float4*)bias)[lane];
    float4 o = make_float4(fmaf(d, a0, bv.x), fmaf(d, a1, bv.y), fmaf(d, a2, bv.z), fmaf(d, a3, bv.w));
    if (do_relu) {
        o.x = fmaxf(o.x, 0.f); o.y = fmaxf(o.y, 0.f);
        o.z = fmaxf(o.z, 0.f); o.w = fmaxf(o.w, 0.f);
    }
    ((float4*)(h + (size_t)wid * 256))[lane] = o;
}

// ---- z'[i] = dinv_i * dot(h[i,:], W2[:,0]) ----
__global__ __launch_bounds__(256) void k_gemv(const float* __restrict__ h, const float* __restrict__ w,
                                              const float* __restrict__ dinv, float* __restrict__ z, int N) {
    int wid = (blockIdx.x * 256 + threadIdx.x) >> 6;
    int lane = threadIdx.x & 63;
    if (wid >= N) return;
    float4 hv = ((const float4*)(h + (size_t)wid * 256))[lane];
    float4 wv = ((const float4*)w)[lane];
    float s = hv.x * wv.x + hv.y * wv.y + hv.z * wv.z + hv.w * wv.w;
#pragma unroll
    for (int off = 32; off > 0; off >>= 1) s += __shfl_down(s, off, 64);
    if (lane == 0) z[wid] = dinv[wid] * s;
}

__global__ __launch_bounds__(256) void k_agg_out(const float* __restrict__ z, float* __restrict__ out,
                                                 const int* __restrict__ rs, const int* __restrict__ col,
                                                 const float* __restrict__ dinv, const float* __restrict__ b2,
                                                 int N) {
    int wid = (blockIdx.x * 256 + threadIdx.x) >> 6;
    int lane = threadIdx.x & 63;
    if (wid >= N) return;
    int e0 = rs[wid], e1 = rs[wid + 1];
    float v = 0.f;
    for (int base = e0; base < e1; base += 64) {
        int e = base + lane;
        if (e < e1) v += z[col[e]];
    }
#pragma unroll
    for (int off = 32; off > 0; off >>= 1) v += __shfl_down(v, off, 64);
    if (lane == 0) out[wid] = fmaf(dinv[wid], v + z[wid], b2[0]);
}

extern "C" void kernel_launch(void* const* d_in, const int* in_sizes, int n_in,
                              void* d_out, int out_size, void* d_ws, size_t ws_size,
                              hipStream_t stream) {
    const float* x  = (const float*)d_in[0];
    const int*   ei = (const int*)d_in[1];
    const float* W0 = (const float*)d_in[2];
    const float* b0 = (const float*)d_in[3];
    const float* W1 = (const float*)d_in[4];
    const float* b1 = (const float*)d_in[5];
    const float* W2 = (const float*)d_in[6];
    const float* b2 = (const float*)d_in[7];
    float* out = (float*)d_out;

    int N = in_sizes[0] / 256;
    int E = in_sizes[1] / 2;
    const int* esrc = ei;
    const int* edst = ei + E;

    char* p = (char*)d_ws;
    unsigned short* tb = (unsigned short*)p; p += alignup((size_t)N * 256 * 2, 16);
    float* h = (float*)p;      p += (size_t)N * 256 * 4;
    unsigned short* Wt0 = (unsigned short*)p; p += 256 * 256 * 2;
    unsigned short* Wt1 = (unsigned short*)p; p += 256 * 256 * 2;
    float* z = (float*)p;      p += alignup((size_t)N * 4, 16);
    float* dinv = (float*)p;   p += alignup((size_t)N * 4, 16);
    int* deg = (int*)p;        p += alignup((size_t)N * 4, 16);
    int* cursor = (int*)p;     p += alignup((size_t)N * 4, 16);
    int* rs = (int*)p;         p += alignup((size_t)(N + 1) * 4, 16);
    int* col = (int*)p;        p += alignup((size_t)E * 4, 16);
    int* bsum = (int*)p;       p += 256 * 4;

    int nb = (N + 1023) / 1024;
    dim3 blk(256);

    k_fill_i32<<<(N + 255) / 256, blk, 0, stream>>>(deg, 0, N);
    k_count_deg<<<(E + 255) / 256, blk, 0, stream>>>(edst, deg, E);
    k_dinv<<<(N + 255) / 256, blk, 0, stream>>>(deg, dinv, N);
    k_scan1<<<nb, blk, 0, stream>>>(deg, rs, bsum, N);
    k_scan2<<<1, blk, 0, stream>>>(bsum, nb);
    k_scan3<<<nb, blk, 0, stream>>>(rs, cursor, bsum, N, E);
    k_fill_csr<<<(E + 255) / 256, blk, 0, stream>>>(esrc, edst, cursor, col, E);
    k_wt<<<256, blk, 0, stream>>>(W0, Wt0);
    k_wt<<<256, blk, 0, stream>>>(W1, Wt1);

    dim3 gg(2, (N + 127) / 128);
    k_gemm_mfma<<<gg, blk, 0, stream>>>(x, Wt0, tb, dinv, N);
    k_agg<<<(N + 3) / 4, blk, 0, stream>>>(tb, h, rs, col, dinv, b0, N, 1);
    k_gemm_mfma<<<gg, blk, 0, stream>>>(h, Wt1, tb, dinv, N);
    k_agg<<<(N + 3) / 4, blk, 0, stream>>>(tb, h, rs, col, dinv, b1, N, 1);
    k_gemv<<<(N + 3) / 4, blk, 0, stream>>>(h, W2, dinv, z, N);
    k_agg_out<<<(N + 3) / 4, blk, 0, stream>>>(z, out, rs, col, dinv, b2, N);
}

// Round 6
// 384.810 us; speedup vs baseline: 1.6468x; 1.0256x over previous
//
#include <hip/hip_runtime.h>

// GCN 3-layer, bf16 datapath end-to-end:
//   xb = bf16(x); t' = bf16(dinv_r * (A_bf16 @ W)) via MFMA (f32 accum)
//   h  = bf16(relu(dinv_i * (sum_nbr t'[s] + t'[i]) + b))   (bf16 gather, f32 accum)
//   z  = dinv_i * dot(h_i, W2); out_i = dinv_i*(sum z[nbr] + z[i]) + b2

static inline size_t alignup(size_t x, size_t a) { return (x + a - 1) & ~(a - 1); }

typedef __attribute__((ext_vector_type(8))) short short8;
typedef __attribute__((ext_vector_type(4))) float f32x4;

__device__ inline unsigned short f2bf(float f) {
    union { float f; unsigned int u; } v; v.f = f;
    unsigned int r = v.u + 0x7FFFu + ((v.u >> 16) & 1u);  // RTNE
    return (unsigned short)(r >> 16);
}
__device__ inline float bf2f(unsigned short u) {
    union { unsigned int u; float f; } v; v.u = ((unsigned int)u) << 16;
    return v.f;
}

// ---------------- preprocessing ----------------
__global__ __launch_bounds__(256) void k_fill_i32(int* __restrict__ p, int v, int n) {
    int i = blockIdx.x * 256 + threadIdx.x;
    if (i < n) p[i] = v;
}

__global__ __launch_bounds__(256) void k_count_deg(const int* __restrict__ dst, int* __restrict__ deg, int E) {
    int e = blockIdx.x * 256 + threadIdx.x;
    if (e < E) atomicAdd(&deg[dst[e]], 1);
}

// scan part 1 + dinv fused
__global__ __launch_bounds__(256) void k_scan1(const int* __restrict__ deg, int* __restrict__ rs,
                                               int* __restrict__ bsum, float* __restrict__ dinv, int n) {
    __shared__ int sd[256];
    int b = blockIdx.x, tid = threadIdx.x;
    int base = b * 1024 + tid * 4;
    int v[4];
#pragma unroll
    for (int j = 0; j < 4; ++j) v[j] = (base + j < n) ? deg[base + j] : 0;
    int tot = v[0] + v[1] + v[2] + v[3];
    sd[tid] = tot;
    for (int off = 1; off < 256; off <<= 1) {
        __syncthreads();
        int t = (tid >= off) ? sd[tid - off] : 0;
        __syncthreads();
        sd[tid] += t;
    }
    __syncthreads();
    int run = tid ? sd[tid - 1] : 0;
#pragma unroll
    for (int j = 0; j < 4; ++j) {
        if (base + j < n) {
            rs[base + j] = run;
            dinv[base + j] = rsqrtf((float)v[j] + 1.0f);  // +1 self-loop
        }
        run += v[j];
    }
    if (tid == 255) bsum[b] = sd[255];
}

__global__ __launch_bounds__(256) void k_scan2(int* __restrict__ bsum, int nb) {
    __shared__ int sd[256];
    int tid = threadIdx.x;
    sd[tid] = (tid < nb) ? bsum[tid] : 0;
    for (int off = 1; off < 256; off <<= 1) {
        __syncthreads();
        int t = (tid >= off) ? sd[tid - off] : 0;
        __syncthreads();
        sd[tid] += t;
    }
    __syncthreads();
    if (tid < nb) bsum[tid] = tid ? sd[tid - 1] : 0;
}

__global__ __launch_bounds__(256) void k_scan3(int* __restrict__ rs, int* __restrict__ cursor,
                                               const int* __restrict__ bsum, int n, int E) {
    int b = blockIdx.x, tid = threadIdx.x;
    int off = bsum[b];
    int base = b * 1024 + tid * 4;
#pragma unroll
    for (int j = 0; j < 4; ++j) {
        int idx = base + j;
        if (idx < n) {
            int v = rs[idx] + off;
            rs[idx] = v;
            cursor[idx] = v;
        }
    }
    if (b == 0 && tid == 0) rs[n] = E;
}

__global__ __launch_bounds__(256) void k_fill_csr(const int* __restrict__ src, const int* __restrict__ dst,
                                                  int* __restrict__ cursor, int* __restrict__ col, int E) {
    int e = blockIdx.x * 256 + threadIdx.x;
    if (e < E) {
        int d = dst[e];
        int pos = atomicAdd(&cursor[d], 1);
        col[pos] = src[e];
    }
}

// ---- both W (f32 [k][n]) -> Wt (bf16 [n][k]) in one launch ----
__global__ __launch_bounds__(256) void k_wt2(const float* __restrict__ W0, const float* __restrict__ W1,
                                             unsigned short* __restrict__ Wt0, unsigned short* __restrict__ Wt1) {
    int idx = blockIdx.x * 256 + threadIdx.x;  // 0..131071
    const float* W = (idx < 65536) ? W0 : W1;
    unsigned short* Wt = (idx < 65536) ? Wt0 : Wt1;
    int id = idx & 65535;
    int k = id >> 8, n = id & 255;
    Wt[(size_t)n * 256 + k] = f2bf(W[(size_t)k * 256 + n]);
}

// ---- x (f32) -> xb (bf16), 8 elems/thread ----
__global__ __launch_bounds__(256) void k_xb(const float* __restrict__ x, unsigned short* __restrict__ xb,
                                            int total8) {
    int i = blockIdx.x * 256 + threadIdx.x;
    if (i >= total8) return;
    float4 f0 = *(const float4*)(x + (size_t)i * 8);
    float4 f1 = *(const float4*)(x + (size_t)i * 8 + 4);
    short8 u;
    u[0] = (short)f2bf(f0.x); u[1] = (short)f2bf(f0.y);
    u[2] = (short)f2bf(f0.z); u[3] = (short)f2bf(f0.w);
    u[4] = (short)f2bf(f1.x); u[5] = (short)f2bf(f1.y);
    u[6] = (short)f2bf(f1.z); u[7] = (short)f2bf(f1.w);
    *(short8*)(xb + (size_t)i * 8) = u;
}

// ---------------- MFMA GEMM (bf16 A) ----------------
// C[r][c] = bf16( dinv[r] * sum_k A[r][k]*W[k][c] ), A bf16 [N][256], Wt bf16 [c][k].
// 128x128 tile, BK=32, 4 waves (2x2), 16 MFMA(16x16x32)/wave/K-step.
// LDS fragment layout: elem(r,k) at ushort idx (r>>4)*512 + (kg)*128 + (r&15)*8 + (k&7), kg=k>>3.
__global__ __launch_bounds__(256) void k_gemm_mfma(const unsigned short* __restrict__ A,
                                                   const unsigned short* __restrict__ Wt,
                                                   unsigned short* __restrict__ C,
                                                   const float* __restrict__ dinv, int N) {
    __shared__ __align__(16) unsigned short As2[128 * 32];
    __shared__ __align__(16) unsigned short Bs2[128 * 32];
    __shared__ __align__(16) unsigned short Cs[4 * 64 * 64];

    int tid = threadIdx.x;
    int lane = tid & 63, w = tid >> 6;
    int wr = w >> 1, wc = w & 1;
    int row0 = blockIdx.y * 128, col0 = blockIdx.x * 128;

    f32x4 acc[4][4];
#pragma unroll
    for (int m = 0; m < 4; ++m)
#pragma unroll
        for (int n = 0; n < 4; ++n) acc[m][n] = (f32x4)0.f;

    for (int k0 = 0; k0 < 256; k0 += 32) {
#pragma unroll
        for (int it = 0; it < 2; ++it) {
            int c = tid + it * 256;
            int r = c >> 2, kg = c & 3;
            int grow = row0 + r;
            short8 u = {0, 0, 0, 0, 0, 0, 0, 0};
            if (grow < N) u = *(const short8*)(A + (size_t)grow * 256 + k0 + kg * 8);
            *(short8*)&As2[(r >> 4) * 512 + kg * 128 + (r & 15) * 8] = u;
        }
#pragma unroll
        for (int it = 0; it < 2; ++it) {
            int c = tid + it * 256;
            int n = c >> 2, kg = c & 3;
            short8 u = *(const short8*)(Wt + (size_t)(col0 + n) * 256 + k0 + kg * 8);
            *(short8*)&Bs2[(n >> 4) * 512 + kg * 128 + (n & 15) * 8] = u;
        }
        __syncthreads();
        short8 af[4], bfr[4];
#pragma unroll
        for (int m = 0; m < 4; ++m)
            af[m] = *(const short8*)&As2[(wr * 4 + m) * 512 + (lane >> 4) * 128 + (lane & 15) * 8];
#pragma unroll
        for (int n = 0; n < 4; ++n)
            bfr[n] = *(const short8*)&Bs2[(wc * 4 + n) * 512 + (lane >> 4) * 128 + (lane & 15) * 8];
#pragma unroll
        for (int m = 0; m < 4; ++m)
#pragma unroll
            for (int n = 0; n < 4; ++n)
                acc[m][n] = __builtin_amdgcn_mfma_f32_16x16x32_bf16(af[m], bfr[n], acc[m][n], 0, 0, 0);
        __syncthreads();
    }

    unsigned short* myCs = &Cs[w * 4096];
#pragma unroll
    for (int m = 0; m < 4; ++m) {
#pragma unroll
        for (int j = 0; j < 4; ++j) {
            int r = m * 16 + (lane >> 4) * 4 + j;  // D: row=(l>>4)*4+reg
            int grow = row0 + wr * 64 + r;
            float d = (grow < N) ? dinv[grow] : 0.f;
#pragma unroll
            for (int n = 0; n < 4; ++n)
                myCs[r * 64 + n * 16 + (lane & 15)] = f2bf(acc[m][n][j] * d);  // D: col=l&15
        }
    }
    __syncthreads();
#pragma unroll
    for (int i = 0; i < 8; ++i) {
        int r = i * 8 + (lane >> 3);
        int grow = row0 + wr * 64 + r;
        if (grow < N) {
            short8 v = *(const short8*)&myCs[r * 64 + (lane & 7) * 8];
            *(short8*)(C + (size_t)grow * 256 + col0 + wc * 64 + (lane & 7) * 8) = v;
        }
    }
}

// ---------------- aggregation over bf16 t', bf16 output ----------------
// one wave per node; lane-halves process even/odd edges; 16B load per lane (8 features).
__global__ __launch_bounds__(256) void k_agg(const unsigned short* __restrict__ t,
                                             unsigned short* __restrict__ h,
                                             const int* __restrict__ rs, const int* __restrict__ col,
                                             const float* __restrict__ dinv, const float* __restrict__ bias,
                                             int N, int do_relu) {
    int wid = (blockIdx.x * 256 + threadIdx.x) >> 6;
    int lane = threadIdx.x & 63;
    if (wid >= N) return;
    int half = lane >> 5, sub = lane & 31;
    const short8* tp = (const short8*)t;  // 32 chunks of 16B per row

    // self term (half 0 only; half 1 contributes 0)
    short8 sv = tp[(size_t)wid * 32 + sub];
    float hsel = (half == 0) ? 1.f : 0.f;
    float a[8];
#pragma unroll
    for (int i = 0; i < 8; ++i) a[i] = hsel * bf2f((unsigned short)sv[i]);

    int e0 = rs[wid], e1 = rs[wid + 1];
    for (int base = e0; base < e1; base += 64) {
        int m = e1 - base; if (m > 64) m = 64;
        int c = (base + lane < e1) ? col[base + lane] : 0;
        int npairs = (m + 1) >> 1;
        int j = 0;
        for (; j + 4 <= npairs; j += 4) {
            int i0 = 2 * j + half, i1 = i0 + 2, i2 = i0 + 4, i3 = i0 + 6;
            int s0 = __shfl(c, i0), s1 = __shfl(c, i1), s2 = __shfl(c, i2), s3 = __shfl(c, i3);
            float f0 = (i0 < m) ? 1.f : 0.f, f1 = (i1 < m) ? 1.f : 0.f;
            float f2 = (i2 < m) ? 1.f : 0.f, f3 = (i3 < m) ? 1.f : 0.f;
            short8 w0 = tp[(size_t)s0 * 32 + sub];
            short8 w1 = tp[(size_t)s1 * 32 + sub];
            short8 w2 = tp[(size_t)s2 * 32 + sub];
            short8 w3 = tp[(size_t)s3 * 32 + sub];
#pragma unroll
            for (int i = 0; i < 8; ++i) {
                a[i] = fmaf(f0, bf2f((unsigned short)w0[i]), a[i]);
                a[i] = fmaf(f1, bf2f((unsigned short)w1[i]), a[i]);
                a[i] = fmaf(f2, bf2f((unsigned short)w2[i]), a[i]);
                a[i] = fmaf(f3, bf2f((unsigned short)w3[i]), a[i]);
            }
        }
        for (; j < npairs; ++j) {
            int i0 = 2 * j + half;
            int s0 = __shfl(c, i0);
            float f0 = (i0 < m) ? 1.f : 0.f;
            short8 w0 = tp[(size_t)s0 * 32 + sub];
#pragma unroll
            for (int i = 0; i < 8; ++i) a[i] = fmaf(f0, bf2f((unsigned short)w0[i]), a[i]);
        }
    }
    // combine halves
#pragma unroll
    for (int i = 0; i < 8; ++i) a[i] += __shfl_xor(a[i], 32, 64);

    if (half == 0) {
        float d = dinv[wid];
        float4 b0 = ((const float4*)bias)[sub * 2];
        float4 b1 = ((const float4*)bias)[sub * 2 + 1];
        float o[8];
        o[0] = fmaf(d, a[0], b0.x); o[1] = fmaf(d, a[1], b0.y);
        o[2] = fmaf(d, a[2], b0.z); o[3] = fmaf(d, a[3], b0.w);
        o[4] = fmaf(d, a[4], b1.x); o[5] = fmaf(d, a[5], b1.y);
        o[6] = fmaf(d, a[6], b1.z); o[7] = fmaf(d, a[7], b1.w);
        short8 u;
#pragma unroll
        for (int i = 0; i < 8; ++i) {
            float v = do_relu ? fmaxf(o[i], 0.f) : o[i];
            u[i] = (short)f2bf(v);
        }
        *(short8*)(h + (size_t)wid * 256 + sub * 8) = u;
    }
}

// ---- z[i] = dinv_i * dot(h_bf16[i,:], W2[:,0]) ----
__global__ __launch_bounds__(256) void k_gemv(const unsigned short* __restrict__ h, const float* __restrict__ w,
                                              const float* __restrict__ dinv, float* __restrict__ z, int N) {
    int wid = (blockIdx.x * 256 + threadIdx.x) >> 6;
    int lane = threadIdx.x & 63;
    if (wid >= N) return;
    ushort4 hv = ((const ushort4*)(h + (size_t)wid * 256))[lane];
    float4 wv = ((const float4*)w)[lane];
    float s = bf2f(hv.x) * wv.x + bf2f(hv.y) * wv.y + bf2f(hv.z) * wv.z + bf2f(hv.w) * wv.w;
#pragma unroll
    for (int off = 32; off > 0; off >>= 1) s += __shfl_down(s, off, 64);
    if (lane == 0) z[wid] = dinv[wid] * s;
}

__global__ __launch_bounds__(256) void k_agg_out(const float* __restrict__ z, float* __restrict__ out,
                                                 const int* __restrict__ rs, const int* __restrict__ col,
                                                 const float* __restrict__ dinv, const float* __restrict__ b2,
                                                 int N) {
    int wid = (blockIdx.x * 256 + threadIdx.x) >> 6;
    int lane = threadIdx.x & 63;
    if (wid >= N) return;
    int e0 = rs[wid], e1 = rs[wid + 1];
    float v = 0.f;
    for (int base = e0; base < e1; base += 64) {
        int e = base + lane;
        if (e < e1) v += z[col[e]];
    }
#pragma unroll
    for (int off = 32; off > 0; off >>= 1) v += __shfl_down(v, off, 64);
    if (lane == 0) out[wid] = fmaf(dinv[wid], v + z[wid], b2[0]);
}

extern "C" void kernel_launch(void* const* d_in, const int* in_sizes, int n_in,
                              void* d_out, int out_size, void* d_ws, size_t ws_size,
                              hipStream_t stream) {
    const float* x  = (const float*)d_in[0];
    const int*   ei = (const int*)d_in[1];
    const float* W0 = (const float*)d_in[2];
    const float* b0 = (const float*)d_in[3];
    const float* W1 = (const float*)d_in[4];
    const float* b1 = (const float*)d_in[5];
    const float* W2 = (const float*)d_in[6];
    const float* b2 = (const float*)d_in[7];
    float* out = (float*)d_out;

    int N = in_sizes[0] / 256;
    int E = in_sizes[1] / 2;
    const int* esrc = ei;
    const int* edst = ei + E;

    char* p = (char*)d_ws;
    unsigned short* tb = (unsigned short*)p; p += alignup((size_t)N * 256 * 2, 16);
    unsigned short* hb = (unsigned short*)p; p += alignup((size_t)N * 256 * 2, 16);
    unsigned short* xb = (unsigned short*)p; p += alignup((size_t)N * 256 * 2, 16);
    unsigned short* Wt0 = (unsigned short*)p; p += 256 * 256 * 2;
    unsigned short* Wt1 = (unsigned short*)p; p += 256 * 256 * 2;
    float* z = (float*)p;      p += alignup((size_t)N * 4, 16);
    float* dinv = (float*)p;   p += alignup((size_t)N * 4, 16);
    int* deg = (int*)p;        p += alignup((size_t)N * 4, 16);
    int* cursor = (int*)p;     p += alignup((size_t)N * 4, 16);
    int* rs = (int*)p;         p += alignup((size_t)(N + 1) * 4, 16);
    int* col = (int*)p;        p += alignup((size_t)E * 4, 16);
    int* bsum = (int*)p;       p += 256 * 4;

    int nb = (N + 1023) / 1024;
    dim3 blk(256);

    k_fill_i32<<<(N + 255) / 256, blk, 0, stream>>>(deg, 0, N);
    k_count_deg<<<(E + 255) / 256, blk, 0, stream>>>(edst, deg, E);
    k_scan1<<<nb, blk, 0, stream>>>(deg, rs, bsum, dinv, N);
    k_scan2<<<1, blk, 0, stream>>>(bsum, nb);
    k_scan3<<<nb, blk, 0, stream>>>(rs, cursor, bsum, N, E);
    k_fill_csr<<<(E + 255) / 256, blk, 0, stream>>>(esrc, edst, cursor, col, E);
    k_wt2<<<512, blk, 0, stream>>>(W0, W1, Wt0, Wt1);
    int total8 = N * 32;  // N*256/8
    k_xb<<<(total8 + 255) / 256, blk, 0, stream>>>(x, xb, total8);

    dim3 gg(2, (N + 127) / 128);
    k_gemm_mfma<<<gg, blk, 0, stream>>>(xb, Wt0, tb, dinv, N);
    k_agg<<<(N + 3) / 4, blk, 0, stream>>>(tb, hb, rs, col, dinv, b0, N, 1);
    k_gemm_mfma<<<gg, blk, 0, stream>>>(hb, Wt1, tb, dinv, N);
    k_agg<<<(N + 3) / 4, blk, 0, stream>>>(tb, hb, rs, col, dinv, b1, N, 1);
    k_gemv<<<(N + 3) / 4, blk, 0, stream>>>(hb, W2, dinv, z, N);
    k_agg_out<<<(N + 3) / 4, blk, 0, stream>>>(z, out, rs, col, dinv, b2, N);
}

// Round 7
// 361.818 us; speedup vs baseline: 1.7515x; 1.0635x over previous
//
#include <hip/hip_runtime.h>

// GCN 3-layer, bf16 datapath:
//   t' = bf16(dinv_r * (A @ W)) via pipelined MFMA (f32 accum); A = f32 x (L0) or bf16 h (L1)
//   h  = bf16(relu(dinv_i * (sum_nbr t'[s] + t'[i]) + b))   (bf16 gather, f32 accum)
//   layer2: fused into agg2 (dot with W2 in-register) -> z; out = dinv*(sum z[nbr]+z[i]) + b2

static inline size_t alignup(size_t x, size_t a) { return (x + a - 1) & ~(a - 1); }

typedef __attribute__((ext_vector_type(8))) short short8;
typedef __attribute__((ext_vector_type(4))) float f32x4;

__device__ inline unsigned short f2bf(float f) {
    union { float f; unsigned int u; } v; v.f = f;
    unsigned int r = v.u + 0x7FFFu + ((v.u >> 16) & 1u);  // RTNE
    return (unsigned short)(r >> 16);
}
__device__ inline float bf2f(unsigned short u) {
    union { unsigned int u; float f; } v; v.u = ((unsigned int)u) << 16;
    return v.f;
}

// ---------------- preprocessing ----------------
__global__ __launch_bounds__(256) void k_fill_i32(int* __restrict__ p, int v, int n) {
    int i = blockIdx.x * 256 + threadIdx.x;
    if (i < n) p[i] = v;
}

__global__ __launch_bounds__(256) void k_count_deg(const int* __restrict__ dst, int* __restrict__ deg, int E) {
    int e = blockIdx.x * 256 + threadIdx.x;
    if (e < E) atomicAdd(&deg[dst[e]], 1);
}

__global__ __launch_bounds__(256) void k_scan1(const int* __restrict__ deg, int* __restrict__ rs,
                                               int* __restrict__ bsum, float* __restrict__ dinv, int n) {
    __shared__ int sd[256];
    int b = blockIdx.x, tid = threadIdx.x;
    int base = b * 1024 + tid * 4;
    int v[4];
#pragma unroll
    for (int j = 0; j < 4; ++j) v[j] = (base + j < n) ? deg[base + j] : 0;
    int tot = v[0] + v[1] + v[2] + v[3];
    sd[tid] = tot;
    for (int off = 1; off < 256; off <<= 1) {
        __syncthreads();
        int t = (tid >= off) ? sd[tid - off] : 0;
        __syncthreads();
        sd[tid] += t;
    }
    __syncthreads();
    int run = tid ? sd[tid - 1] : 0;
#pragma unroll
    for (int j = 0; j < 4; ++j) {
        if (base + j < n) {
            rs[base + j] = run;
            dinv[base + j] = rsqrtf((float)v[j] + 1.0f);
        }
        run += v[j];
    }
    if (tid == 255) bsum[b] = sd[255];
}

__global__ __launch_bounds__(256) void k_scan2(int* __restrict__ bsum, int nb) {
    __shared__ int sd[256];
    int tid = threadIdx.x;
    sd[tid] = (tid < nb) ? bsum[tid] : 0;
    for (int off = 1; off < 256; off <<= 1) {
        __syncthreads();
        int t = (tid >= off) ? sd[tid - off] : 0;
        __syncthreads();
        sd[tid] += t;
    }
    __syncthreads();
    if (tid < nb) bsum[tid] = tid ? sd[tid - 1] : 0;
}

__global__ __launch_bounds__(256) void k_scan3(int* __restrict__ rs, int* __restrict__ cursor,
                                               const int* __restrict__ bsum, int n, int E) {
    int b = blockIdx.x, tid = threadIdx.x;
    int off = bsum[b];
    int base = b * 1024 + tid * 4;
#pragma unroll
    for (int j = 0; j < 4; ++j) {
        int idx = base + j;
        if (idx < n) {
            int v = rs[idx] + off;
            rs[idx] = v;
            cursor[idx] = v;
        }
    }
    if (b == 0 && tid == 0) rs[n] = E;
}

__global__ __launch_bounds__(256) void k_fill_csr(const int* __restrict__ src, const int* __restrict__ dst,
                                                  int* __restrict__ cursor, int* __restrict__ col, int E) {
    int e = blockIdx.x * 256 + threadIdx.x;
    if (e < E) {
        int d = dst[e];
        int pos = atomicAdd(&cursor[d], 1);
        col[pos] = src[e];
    }
}

__global__ __launch_bounds__(256) void k_wt2(const float* __restrict__ W0, const float* __restrict__ W1,
                                             unsigned short* __restrict__ Wt0, unsigned short* __restrict__ Wt1) {
    int idx = blockIdx.x * 256 + threadIdx.x;  // 0..131071
    const float* W = (idx < 65536) ? W0 : W1;
    unsigned short* Wt = (idx < 65536) ? Wt0 : Wt1;
    int id = idx & 65535;
    int k = id >> 8, n = id & 255;
    Wt[(size_t)n * 256 + k] = f2bf(W[(size_t)k * 256 + n]);
}

// ---------------- pipelined MFMA GEMM ----------------
// C[r][c] = bf16( dinv[r] * sum_k A[r][k]*W[k][c] ); A f32 (AF32) or bf16; Wt bf16 [c][k].
// 128x128 tile, BK=32, 4 waves (2x2). Reg-staged prefetch: load k+1 -> regs, MFMA k, then ds_write.
// LDS 32KB: As(8K)+Bs(8K) staging, 32KB Cs epilogue aliases everything.
template <bool AF32>
__global__ __launch_bounds__(256) void k_gemm_mfma(const void* __restrict__ Ap,
                                                   const unsigned short* __restrict__ Wt,
                                                   unsigned short* __restrict__ C,
                                                   const float* __restrict__ dinv, int N) {
    __shared__ __align__(16) unsigned short smem[16384];  // 32 KB
    unsigned short* As2 = smem;          // 128*32 ushort
    unsigned short* Bs2 = smem + 4096;
    unsigned short* Cs = smem;           // epilogue alias (16384 ushort)

    int tid = threadIdx.x;
    int lane = tid & 63, w = tid >> 6;
    int wr = w >> 1, wc = w & 1;
    int row0 = blockIdx.y * 128, col0 = blockIdx.x * 128;

    f32x4 acc[4][4];
#pragma unroll
    for (int m = 0; m < 4; ++m)
#pragma unroll
        for (int n = 0; n < 4; ++n) acc[m][n] = (f32x4)0.f;

    const int c0 = tid, c1 = tid + 256;
    const int ar0 = c0 >> 2, akg0 = c0 & 3, ar1 = c1 >> 2, akg1 = c1 & 3;

    auto loadA = [&](int r, int kg, int k0) -> short8 {
        short8 u = {0, 0, 0, 0, 0, 0, 0, 0};
        int grow = row0 + r;
        if (grow < N) {
            if constexpr (AF32) {
                const float* g = (const float*)Ap + (size_t)grow * 256 + k0 + kg * 8;
                float4 f0 = *(const float4*)g;
                float4 f1 = *(const float4*)(g + 4);
                u[0] = (short)f2bf(f0.x); u[1] = (short)f2bf(f0.y);
                u[2] = (short)f2bf(f0.z); u[3] = (short)f2bf(f0.w);
                u[4] = (short)f2bf(f1.x); u[5] = (short)f2bf(f1.y);
                u[6] = (short)f2bf(f1.z); u[7] = (short)f2bf(f1.w);
            } else {
                u = *(const short8*)((const unsigned short*)Ap + (size_t)grow * 256 + k0 + kg * 8);
            }
        }
        return u;
    };
    auto loadB = [&](int n, int kg, int k0) -> short8 {
        return *(const short8*)(Wt + (size_t)(col0 + n) * 256 + k0 + kg * 8);
    };
    auto stash = [&](short8 a0, short8 a1, short8 b0, short8 b1) {
        *(short8*)&As2[(ar0 >> 4) * 512 + akg0 * 128 + (ar0 & 15) * 8] = a0;
        *(short8*)&As2[(ar1 >> 4) * 512 + akg1 * 128 + (ar1 & 15) * 8] = a1;
        *(short8*)&Bs2[(ar0 >> 4) * 512 + akg0 * 128 + (ar0 & 15) * 8] = b0;
        *(short8*)&Bs2[(ar1 >> 4) * 512 + akg1 * 128 + (ar1 & 15) * 8] = b1;
    };

    // prologue: stage k=0
    {
        short8 a0 = loadA(ar0, akg0, 0), a1 = loadA(ar1, akg1, 0);
        short8 b0 = loadB(ar0, akg0, 0), b1 = loadB(ar1, akg1, 0);
        stash(a0, a1, b0, b1);
    }
    __syncthreads();

#pragma unroll
    for (int i = 0; i < 8; ++i) {
        short8 na0, na1, nb0, nb1;
        if (i < 7) {  // issue next-step loads (in flight across MFMA)
            int k0 = i * 32 + 32;
            na0 = loadA(ar0, akg0, k0); na1 = loadA(ar1, akg1, k0);
            nb0 = loadB(ar0, akg0, k0); nb1 = loadB(ar1, akg1, k0);
        }
        short8 af[4], bfr[4];
#pragma unroll
        for (int m = 0; m < 4; ++m)
            af[m] = *(const short8*)&As2[(wr * 4 + m) * 512 + (lane >> 4) * 128 + (lane & 15) * 8];
#pragma unroll
        for (int n = 0; n < 4; ++n)
            bfr[n] = *(const short8*)&Bs2[(wc * 4 + n) * 512 + (lane >> 4) * 128 + (lane & 15) * 8];
#pragma unroll
        for (int m = 0; m < 4; ++m)
#pragma unroll
            for (int n = 0; n < 4; ++n)
                acc[m][n] = __builtin_amdgcn_mfma_f32_16x16x32_bf16(af[m], bfr[n], acc[m][n], 0, 0, 0);
        if (i < 7) {
            __syncthreads();           // all waves done reading this step's LDS
            stash(na0, na1, nb0, nb1); // compiler waits vmcnt here, after MFMA issued
            __syncthreads();
        }
    }
    __syncthreads();  // LDS about to be reused as Cs

    unsigned short* myCs = &Cs[w * 4096];
#pragma unroll
    for (int m = 0; m < 4; ++m) {
#pragma unroll
        for (int j = 0; j < 4; ++j) {
            int r = m * 16 + (lane >> 4) * 4 + j;  // D: row=(l>>4)*4+reg
            int grow = row0 + wr * 64 + r;
            float d = (grow < N) ? dinv[grow] : 0.f;
#pragma unroll
            for (int n = 0; n < 4; ++n)
                myCs[r * 64 + n * 16 + (lane & 15)] = f2bf(acc[m][n][j] * d);  // D: col=l&15
        }
    }
    __syncthreads();
#pragma unroll
    for (int i = 0; i < 8; ++i) {
        int r = i * 8 + (lane >> 3);
        int grow = row0 + wr * 64 + r;
        if (grow < N) {
            short8 v = *(const short8*)&myCs[r * 64 + (lane & 7) * 8];
            *(short8*)(C + (size_t)grow * 256 + col0 + wc * 64 + (lane & 7) * 8) = v;
        }
    }
}

// ---------------- aggregation over bf16 t' ----------------
// one wave per node; lane-halves process even/odd edges; 16B load per lane.
// FUSE_GEMV: also computes z[node] = dinv*dot(relu(h), W2) and skips the h write.
template <bool FUSE_GEMV>
__global__ __launch_bounds__(256) void k_agg(const unsigned short* __restrict__ t,
                                             unsigned short* __restrict__ h,
                                             const int* __restrict__ rs, const int* __restrict__ col,
                                             const float* __restrict__ dinv, const float* __restrict__ bias,
                                             const float* __restrict__ W2, float* __restrict__ z,
                                             int N) {
    int wid = (blockIdx.x * 256 + threadIdx.x) >> 6;
    int lane = threadIdx.x & 63;
    if (wid >= N) return;
    int half = lane >> 5, sub = lane & 31;
    const short8* tp = (const short8*)t;

    short8 sv = tp[(size_t)wid * 32 + sub];
    float hsel = (half == 0) ? 1.f : 0.f;
    float a[8];
#pragma unroll
    for (int i = 0; i < 8; ++i) a[i] = hsel * bf2f((unsigned short)sv[i]);

    int e0 = rs[wid], e1 = rs[wid + 1];
    for (int base = e0; base < e1; base += 64) {
        int m = e1 - base; if (m > 64) m = 64;
        int c = (base + lane < e1) ? col[base + lane] : 0;
        int npairs = (m + 1) >> 1;
        int j = 0;
        for (; j + 4 <= npairs; j += 4) {
            int i0 = 2 * j + half, i1 = i0 + 2, i2 = i0 + 4, i3 = i0 + 6;
            int s0 = __shfl(c, i0), s1 = __shfl(c, i1), s2 = __shfl(c, i2), s3 = __shfl(c, i3);
            float f0 = (i0 < m) ? 1.f : 0.f, f1 = (i1 < m) ? 1.f : 0.f;
            float f2 = (i2 < m) ? 1.f : 0.f, f3 = (i3 < m) ? 1.f : 0.f;
            short8 w0 = tp[(size_t)s0 * 32 + sub];
            short8 w1 = tp[(size_t)s1 * 32 + sub];
            short8 w2 = tp[(size_t)s2 * 32 + sub];
            short8 w3 = tp[(size_t)s3 * 32 + sub];
#pragma unroll
            for (int i = 0; i < 8; ++i) {
                a[i] = fmaf(f0, bf2f((unsigned short)w0[i]), a[i]);
                a[i] = fmaf(f1, bf2f((unsigned short)w1[i]), a[i]);
                a[i] = fmaf(f2, bf2f((unsigned short)w2[i]), a[i]);
                a[i] = fmaf(f3, bf2f((unsigned short)w3[i]), a[i]);
            }
        }
        for (; j < npairs; ++j) {
            int i0 = 2 * j + half;
            int s0 = __shfl(c, i0);
            float f0 = (i0 < m) ? 1.f : 0.f;
            short8 w0 = tp[(size_t)s0 * 32 + sub];
#pragma unroll
            for (int i = 0; i < 8; ++i) a[i] = fmaf(f0, bf2f((unsigned short)w0[i]), a[i]);
        }
    }
#pragma unroll
    for (int i = 0; i < 8; ++i) a[i] += __shfl_xor(a[i], 32, 64);  // both halves hold full sums

    float d = dinv[wid];
    float4 b0 = ((const float4*)bias)[sub * 2];
    float4 b1 = ((const float4*)bias)[sub * 2 + 1];
    float o[8];
    o[0] = fmaf(d, a[0], b0.x); o[1] = fmaf(d, a[1], b0.y);
    o[2] = fmaf(d, a[2], b0.z); o[3] = fmaf(d, a[3], b0.w);
    o[4] = fmaf(d, a[4], b1.x); o[5] = fmaf(d, a[5], b1.y);
    o[6] = fmaf(d, a[6], b1.z); o[7] = fmaf(d, a[7], b1.w);
#pragma unroll
    for (int i = 0; i < 8; ++i) o[i] = fmaxf(o[i], 0.f);  // both layers relu

    if constexpr (FUSE_GEMV) {
        float4 wv0 = ((const float4*)W2)[sub * 2];
        float4 wv1 = ((const float4*)W2)[sub * 2 + 1];
        float zp = o[0] * wv0.x + o[1] * wv0.y + o[2] * wv0.z + o[3] * wv0.w +
                   o[4] * wv1.x + o[5] * wv1.y + o[6] * wv1.z + o[7] * wv1.w;
#pragma unroll
        for (int off = 16; off > 0; off >>= 1) zp += __shfl_down(zp, off, 32);  // within half
        if (lane == 0) z[wid] = d * zp;
    } else {
        if (half == 0) {
            short8 u;
#pragma unroll
            for (int i = 0; i < 8; ++i) u[i] = (short)f2bf(o[i]);
            *(short8*)(h + (size_t)wid * 256 + sub * 8) = u;
        }
    }
}

__global__ __launch_bounds__(256) void k_agg_out(const float* __restrict__ z, float* __restrict__ out,
                                                 const int* __restrict__ rs, const int* __restrict__ col,
                                                 const float* __restrict__ dinv, const float* __restrict__ b2,
                                                 int N) {
    int wid = (blockIdx.x * 256 + threadIdx.x) >> 6;
    int lane = threadIdx.x & 63;
    if (wid >= N) return;
    int e0 = rs[wid], e1 = rs[wid + 1];
    float v = 0.f;
    for (int base = e0; base < e1; base += 64) {
        int e = base + lane;
        if (e < e1) v += z[col[e]];
    }
#pragma unroll
    for (int off = 32; off > 0; off >>= 1) v += __shfl_down(v, off, 64);
    if (lane == 0) out[wid] = fmaf(dinv[wid], v + z[wid], b2[0]);
}

extern "C" void kernel_launch(void* const* d_in, const int* in_sizes, int n_in,
                              void* d_out, int out_size, void* d_ws, size_t ws_size,
                              hipStream_t stream) {
    const float* x  = (const float*)d_in[0];
    const int*   ei = (const int*)d_in[1];
    const float* W0 = (const float*)d_in[2];
    const float* b0 = (const float*)d_in[3];
    const float* W1 = (const float*)d_in[4];
    const float* b1 = (const float*)d_in[5];
    const float* W2 = (const float*)d_in[6];
    const float* b2 = (const float*)d_in[7];
    float* out = (float*)d_out;

    int N = in_sizes[0] / 256;
    int E = in_sizes[1] / 2;
    const int* esrc = ei;
    const int* edst = ei + E;

    char* p = (char*)d_ws;
    unsigned short* tb = (unsigned short*)p; p += alignup((size_t)N * 256 * 2, 16);
    unsigned short* hb = (unsigned short*)p; p += alignup((size_t)N * 256 * 2, 16);
    unsigned short* Wt0 = (unsigned short*)p; p += 256 * 256 * 2;
    unsigned short* Wt1 = (unsigned short*)p; p += 256 * 256 * 2;
    float* z = (float*)p;      p += alignup((size_t)N * 4, 16);
    float* dinv = (float*)p;   p += alignup((size_t)N * 4, 16);
    int* deg = (int*)p;        p += alignup((size_t)N * 4, 16);
    int* cursor = (int*)p;     p += alignup((size_t)N * 4, 16);
    int* rs = (int*)p;         p += alignup((size_t)(N + 1) * 4, 16);
    int* col = (int*)p;        p += alignup((size_t)E * 4, 16);
    int* bsum = (int*)p;       p += 256 * 4;

    int nb = (N + 1023) / 1024;
    dim3 blk(256);

    k_fill_i32<<<(N + 255) / 256, blk, 0, stream>>>(deg, 0, N);
    k_count_deg<<<(E + 255) / 256, blk, 0, stream>>>(edst, deg, E);
    k_scan1<<<nb, blk, 0, stream>>>(deg, rs, bsum, dinv, N);
    k_scan2<<<1, blk, 0, stream>>>(bsum, nb);
    k_scan3<<<nb, blk, 0, stream>>>(rs, cursor, bsum, N, E);
    k_fill_csr<<<(E + 255) / 256, blk, 0, stream>>>(esrc, edst, cursor, col, E);
    k_wt2<<<512, blk, 0, stream>>>(W0, W1, Wt0, Wt1);

    dim3 gg(2, (N + 127) / 128);
    k_gemm_mfma<true><<<gg, blk, 0, stream>>>(x, Wt0, tb, dinv, N);
    k_agg<false><<<(N + 3) / 4, blk, 0, stream>>>(tb, hb, rs, col, dinv, b0, nullptr, nullptr, N);
    k_gemm_mfma<false><<<gg, blk, 0, stream>>>(hb, Wt1, tb, dinv, N);
    k_agg<true><<<(N + 3) / 4, blk, 0, stream>>>(tb, nullptr, rs, col, dinv, b1, W2, z, N);
    k_agg_out<<<(N + 3) / 4, blk, 0, stream>>>(z, out, rs, col, dinv, b2, N);
}